// Round 1
// baseline (490.896 us; speedup 1.0000x reference)
//
#include <hip/hip_runtime.h>

typedef unsigned short u16;
typedef unsigned int u32;
typedef __attribute__((ext_vector_type(8))) short short8;   // 8 x bf16
typedef __attribute__((ext_vector_type(4))) float f32x4;

// ---------------- workspace layout (bytes) ----------------
#define OFF_WMEAN 0        // float[801]: wmean[0..799] (zero-padded past 784), [800]=mean(b_in)
#define OFF_WINBT 3584     // u16 [128][800]  W_in^T bf16, K padded to 800 with zeros
#define OFF_WEG   208384   // u16 [272][192]  [experts(256) | gate(4) | pad(12)]^T bf16
#define OFF_WCTX  312832   // u16 [2][8][64][8] W_ctx in MFMA-B-fragment-linear order

// ---------------- LDS layout (bytes) ----------------
#define L_ENH 0        // u16 [6][64][40] enhanced tile, chunked (30720 B)
#define L_X   30720    // u16 [64][40]  x chunk           (aliases WEG region)
#define L_WIN 35840    // u16 [128][40] W_in chunk        (aliases WEG region)
#define L_WEG 30720    // u16 [272][40] expert W chunk (21760 B)
#define L_CMB 30720    // u16 [2][64][40] combined tile   (aliases WEG region)
#define L_CTX 0        // u16 [64][132] ctx tile          (aliases ENH region)
#define L_T   52480    // float[64] per-row t
#define L_G   52736    // float[64][4] gate
#define LDS_BYTES 53760

__device__ __forceinline__ u16 f2bf(float x) {
  union { float f; u32 u; } v; v.f = x;
  u32 r = v.u + 0x7FFFu + ((v.u >> 16) & 1u);   // RNE
  return (u16)(r >> 16);
}
__device__ __forceinline__ float bf2f(u16 h) {
  union { u32 u; float f; } v; v.u = ((u32)h) << 16;
  return v.f;
}

// ------------------------------------------------------------------
// Prep: fold W_in row-means into wmean (exact fp32 path for t),
// convert weights to bf16 in MFMA-friendly layouts.
// ------------------------------------------------------------------
__global__ void prep_kernel(const float* __restrict__ W_in, const float* __restrict__ b_in,
                            const float* __restrict__ W_gate, const float* __restrict__ W_exp,
                            const float* __restrict__ W_ctx,
                            float* __restrict__ wm, u16* __restrict__ WinBT,
                            u16* __restrict__ Weg, u16* __restrict__ WctxF) {
  int idx = blockIdx.x * 256 + threadIdx.x;
  if (idx < 801) {
    if (idx == 800) {
      float s = 0.f;
      for (int j = 0; j < 128; ++j) s += b_in[j];
      wm[800] = s * (1.f / 128.f);
    } else if (idx >= 784) {
      wm[idx] = 0.f;
    } else {
      float s = 0.f;
      for (int j = 0; j < 128; ++j) s += W_in[idx * 128 + j];
      wm[idx] = s * (1.f / 128.f);
    }
  } else if (idx < 103201) {                    // WinBT: 128*800
    int j = idx - 801;
    int n = j / 800, k = j - n * 800;
    WinBT[j] = (k < 784) ? f2bf(W_in[k * 128 + n]) : (u16)0;
  } else if (idx < 155425) {                    // Weg: 272*192
    int j = idx - 103201;
    int n = j / 192, k = j - n * 192;
    float v = 0.f;
    if (n < 256) { int e = n >> 6, h = n & 63; v = W_exp[(e * 192 + k) * 64 + h]; }
    else if (n < 260) v = W_gate[k * 4 + (n - 256)];
    Weg[j] = f2bf(v);
  } else if (idx < 163617) {                    // WctxF: 2*8*64*8 fragment-linear
    int f = idx - 155425;
    int jj = f & 7, lane = (f >> 3) & 63, tile = f >> 9;
    int ct = tile & 7, kt = tile >> 3;
    int k = kt * 32 + (lane >> 4) * 8 + jj, n = ct * 16 + (lane & 15);
    WctxF[f] = f2bf(W_ctx[k * 128 + n]);
  }
}

// ------------------------------------------------------------------
// Fused forward: 64 rows per WG, 4 waves (16 rows each), 16x16x32 bf16 MFMA
// ------------------------------------------------------------------
__global__ __launch_bounds__(256, 2)
void fused_kernel(const float* __restrict__ x,
                  const float* __restrict__ b_in, const float* __restrict__ b_gate,
                  const float* __restrict__ b_exp, const float* __restrict__ b_ctx,
                  const float* __restrict__ W_out, const float* __restrict__ b_out,
                  const float* __restrict__ wm, const u16* __restrict__ WinBT,
                  const u16* __restrict__ Weg, const u16* __restrict__ WctxF,
                  float* __restrict__ out) {
  __shared__ __align__(16) char smem[LDS_BYTES];
  u16* lds_enh = (u16*)(smem + L_ENH);
  u16* lds_x   = (u16*)(smem + L_X);
  u16* lds_w   = (u16*)(smem + L_WIN);
  u16* lds_weg = (u16*)(smem + L_WEG);
  u16* lds_cmb = (u16*)(smem + L_CMB);
  u16* lds_ctx = (u16*)(smem + L_CTX);
  float* lds_t = (float*)(smem + L_T);
  float* lds_g = (float*)(smem + L_G);

  const int tid = threadIdx.x;
  const int wv = tid >> 6;        // wave 0..3
  const int ln = tid & 63;
  const int cb = ln & 15;         // fragment col / row-in-tile
  const int qr = ln >> 4;         // k-quad
  const int row0 = blockIdx.x * 64;

  // staging roles for x (4 threads/row, 8 floats each) and W (2 threads/row, 16 bf16 each)
  const int lr = tid >> 2;
  const int ls = tid & 3;
  const float* xrow = x + (size_t)(row0 + lr) * 784;
  const u16* wrow = WinBT + (tid >> 1) * 800 + (tid & 1) * 16;
  const int woff = (tid >> 1) * 40 + (tid & 1) * 16;

  const f32x4 vzero = {0.f, 0.f, 0.f, 0.f};
  f32x4 acc[8];
  #pragma unroll
  for (int i = 0; i < 8; ++i) acc[i] = vzero;

  float tpart = 0.f;
  float4 xr0[2], xr1[2];
  int4 wr0[2], wr1[2];

  // ---- Phase 1: projected = x @ W_in (bf16 MFMA) + exact fp32 t ----
  #pragma unroll
  for (int s = 0; s < 2; ++s) {   // preload chunks 0,1 (always in range)
    int k0 = s * 32;
    xr0[s] = *(const float4*)(xrow + k0 + ls * 8);
    xr1[s] = *(const float4*)(xrow + k0 + ls * 8 + 4);
    wr0[s] = *(const int4*)(wrow + k0);
    wr1[s] = *(const int4*)(wrow + k0 + 8);
  }

  for (int kt = 0; kt < 25; ++kt) {
    const int slot = kt & 1;
    const int k0 = kt * 32;
    __syncthreads();              // LDS consumers of previous chunk done
    {
      float4 a0 = xr0[slot], a1 = xr1[slot];
      const float4 m0 = *(const float4*)(wm + k0 + ls * 8);
      const float4 m1 = *(const float4*)(wm + k0 + ls * 8 + 4);
      tpart += a0.x * m0.x + a0.y * m0.y + a0.z * m0.z + a0.w * m0.w
             + a1.x * m1.x + a1.y * m1.y + a1.z * m1.z + a1.w * m1.w;
      u32 p0 = (u32)f2bf(a0.x) | ((u32)f2bf(a0.y) << 16);
      u32 p1 = (u32)f2bf(a0.z) | ((u32)f2bf(a0.w) << 16);
      u32 p2 = (u32)f2bf(a1.x) | ((u32)f2bf(a1.y) << 16);
      u32 p3 = (u32)f2bf(a1.z) | ((u32)f2bf(a1.w) << 16);
      *(uint4*)(lds_x + lr * 40 + ls * 8) = make_uint4(p0, p1, p2, p3);
      *(int4*)(lds_w + woff)     = wr0[slot];
      *(int4*)(lds_w + woff + 8) = wr1[slot];
    }
    __syncthreads();              // LDS ready
    if (kt + 2 < 25) {            // prefetch 2 chunks ahead into freed slot
      int kn = (kt + 2) * 32;
      bool xok = (kn + ls * 8) < 784;   // K-tail 784..799 is zero pad
      if (xok) {
        xr0[slot] = *(const float4*)(xrow + kn + ls * 8);
        xr1[slot] = *(const float4*)(xrow + kn + ls * 8 + 4);
      } else {
        xr0[slot] = make_float4(0.f, 0.f, 0.f, 0.f);
        xr1[slot] = make_float4(0.f, 0.f, 0.f, 0.f);
      }
      wr0[slot] = *(const int4*)(wrow + kn);
      wr1[slot] = *(const int4*)(wrow + kn + 8);
    }
    short8 Af = *(const short8*)(lds_x + (16 * wv + cb) * 40 + qr * 8);
    #pragma unroll
    for (int ct = 0; ct < 8; ++ct) {
      short8 Bf = *(const short8*)(lds_w + (cb + 16 * ct) * 40 + qr * 8);
      acc[ct] = __builtin_amdgcn_mfma_f32_16x16x32_bf16(Af, Bf, acc[ct], 0, 0, 0);
    }
  }

  // t reduction across the 4 staging threads of each row
  tpart += __shfl_xor(tpart, 1);
  tpart += __shfl_xor(tpart, 2);
  if (ls == 0) lds_t[lr] = tpart;
  __syncthreads();

  // epilogue 1: projected(+b_in) -> enhanced LDS (bf16, chunked [6][64][40])
  #pragma unroll
  for (int ct = 0; ct < 8; ++ct) {
    float bi = b_in[ct * 16 + cb];
    #pragma unroll
    for (int i = 0; i < 4; ++i) {
      int r = 16 * wv + qr * 4 + i;       // C-layout: row=(lane>>4)*4+reg
      int c = ct * 16 + cb;
      lds_enh[(c >> 5) * 2560 + r * 40 + (c & 31)] = f2bf(acc[ct][i] + bi);
    }
  }
  // phasor bank: one thread per row, rotation recurrence from accurate sincosf
  if (tid < 64) {
    float t = lds_t[tid] + wm[800];
    float s1, c1;
    sincosf(7.f * t, &s1, &c1);
    float ck = c1, sk = s1;
    #pragma unroll
    for (int k = 0; k < 32; ++k) {
      int ccol = 128 + k, scol = 160 + k;
      lds_enh[(ccol >> 5) * 2560 + tid * 40 + (ccol & 31)] = f2bf(ck);
      lds_enh[(scol >> 5) * 2560 + tid * 40 + (scol & 31)] = f2bf(sk);
      float nc = ck * c1 - sk * s1;
      sk = sk * c1 + ck * s1;
      ck = nc;
    }
  }

  // ---- Phase 2: experts(256 cols) + gate(4 cols) GEMM, K=192 ----
  f32x4 acc2[17];
  #pragma unroll
  for (int i = 0; i < 17; ++i) acc2[i] = vzero;

  for (int kt = 0; kt < 6; ++kt) {
    __syncthreads();
    const int k0 = kt * 32;
    #pragma unroll
    for (int p = 0; p < 3; ++p) {     // stage Weg chunk [272][32] -> LDS [272][40]
      int tau = tid + p * 256;
      if (tau < 544) {
        int n = tau >> 1, h = tau & 1;
        const u16* src = Weg + n * 192 + k0 + h * 16;
        *(int4*)(lds_weg + n * 40 + h * 16)     = *(const int4*)(src);
        *(int4*)(lds_weg + n * 40 + h * 16 + 8) = *(const int4*)(src + 8);
      }
    }
    __syncthreads();
    short8 Af = *(const short8*)(lds_enh + kt * 2560 + (16 * wv + cb) * 40 + qr * 8);
    #pragma unroll
    for (int ct = 0; ct < 17; ++ct) {
      short8 Bf = *(const short8*)(lds_weg + (cb + 16 * ct) * 40 + qr * 8);
      acc2[ct] = __builtin_amdgcn_mfma_f32_16x16x32_bf16(Af, Bf, acc2[ct], 0, 0, 0);
    }
  }

  // gate softmax across the 4 gate columns (lanes cb=0..3 of each quad)
  {
    float bg = b_gate[cb & 3];
    float g[4];
    #pragma unroll
    for (int i = 0; i < 4; ++i) {
      float gi = acc2[16][i] + bg;
      float m = fmaxf(gi, __shfl_xor(gi, 1));
      m = fmaxf(m, __shfl_xor(m, 2));
      float e = __expf(gi - m);
      float ss = e + __shfl_xor(e, 1);
      ss = ss + __shfl_xor(ss, 2);
      g[i] = e / ss;
    }
    if (cb < 4) {
      #pragma unroll
      for (int i = 0; i < 4; ++i) lds_g[(16 * wv + qr * 4 + i) * 4 + cb] = g[i];
    }
  }
  __syncthreads();

  // relu(+b_exp) then gate-weighted combine -> combined LDS (bf16, [2][64][40])
  #pragma unroll
  for (int ct = 0; ct < 16; ++ct) {
    float be = b_exp[ct * 16 + cb];
    #pragma unroll
    for (int i = 0; i < 4; ++i) acc2[ct][i] = fmaxf(acc2[ct][i] + be, 0.f);
  }
  #pragma unroll
  for (int hi = 0; hi < 4; ++hi) {
    #pragma unroll
    for (int i = 0; i < 4; ++i) {
      int r = 16 * wv + qr * 4 + i;
      float cv = lds_g[r * 4 + 0] * acc2[hi][i]
               + lds_g[r * 4 + 1] * acc2[4 + hi][i]
               + lds_g[r * 4 + 2] * acc2[8 + hi][i]
               + lds_g[r * 4 + 3] * acc2[12 + hi][i];
      int h = hi * 16 + cb;
      lds_cmb[(h >> 5) * 2560 + r * 40 + (h & 31)] = f2bf(cv);
    }
  }
  __syncthreads();

  // ---- Phase 3: ctx = tanh(combined @ W_ctx + b_ctx), K=64, N=128 ----
  f32x4 acc3[8];
  #pragma unroll
  for (int i = 0; i < 8; ++i) acc3[i] = vzero;
  #pragma unroll
  for (int kt2 = 0; kt2 < 2; ++kt2) {
    short8 Af = *(const short8*)(lds_cmb + kt2 * 2560 + (16 * wv + cb) * 40 + qr * 8);
    #pragma unroll
    for (int ct = 0; ct < 8; ++ct) {
      short8 Bf = *(const short8*)(WctxF + ((kt2 * 8 + ct) * 64 + ln) * 8);  // frag-linear, coalesced
      acc3[ct] = __builtin_amdgcn_mfma_f32_16x16x32_bf16(Af, Bf, acc3[ct], 0, 0, 0);
    }
  }
  #pragma unroll
  for (int ct = 0; ct < 8; ++ct) {
    float bc = b_ctx[ct * 16 + cb];
    #pragma unroll
    for (int i = 0; i < 4; ++i) {
      int r = 16 * wv + qr * 4 + i;
      lds_ctx[r * 132 + ct * 16 + cb] = f2bf(tanhf(acc3[ct][i] + bc));
    }
  }
  __syncthreads();

  // ---- Phase 4: logits = ctx @ W_out + b_out (tiny, VALU fp32) ----
  if (tid < 192) {
    int r = tid / 3, c = tid - r * 3;
    float s = b_out[c];
    const u16* cr = lds_ctx + r * 132;
    #pragma unroll 8
    for (int k = 0; k < 128; ++k) s += bf2f(cr[k]) * W_out[k * 3 + c];
    out[(size_t)(row0 + r) * 3 + c] = s;
  }
}

extern "C" void kernel_launch(void* const* d_in, const int* in_sizes, int n_in,
                              void* d_out, int out_size, void* d_ws, size_t ws_size,
                              hipStream_t stream) {
  const float* x      = (const float*)d_in[0];
  const float* W_in   = (const float*)d_in[1];
  const float* b_in   = (const float*)d_in[2];
  const float* W_gate = (const float*)d_in[3];
  const float* b_gate = (const float*)d_in[4];
  const float* W_exp  = (const float*)d_in[5];
  const float* b_exp  = (const float*)d_in[6];
  const float* W_ctx  = (const float*)d_in[7];
  const float* b_ctx  = (const float*)d_in[8];
  const float* W_out  = (const float*)d_in[9];
  const float* b_out  = (const float*)d_in[10];
  float* out = (float*)d_out;

  char* ws = (char*)d_ws;
  float* wm    = (float*)(ws + OFF_WMEAN);
  u16* WinBT   = (u16*)(ws + OFF_WINBT);
  u16* Weg     = (u16*)(ws + OFF_WEG);
  u16* WctxF   = (u16*)(ws + OFF_WCTX);

  const int B = in_sizes[0] / 784;
  prep_kernel<<<640, 256, 0, stream>>>(W_in, b_in, W_gate, W_exp, W_ctx,
                                       wm, WinBT, Weg, WctxF);
  fused_kernel<<<B / 64, 256, 0, stream>>>(x, b_in, b_gate, b_exp, b_ctx,
                                           W_out, b_out, wm, WinBT, Weg, WctxF, out);
}

// Round 2
// 343.054 us; speedup vs baseline: 1.4310x; 1.4310x over previous
//
#include <hip/hip_runtime.h>

typedef unsigned short u16;
typedef unsigned int u32;
typedef __attribute__((ext_vector_type(8))) short short8;   // 8 x bf16
typedef __attribute__((ext_vector_type(4))) float f32x4;

// ---------------- workspace layout (bytes) ----------------
#define OFF_WM    0         // float[801]: wmean[0..799] (pad 0), [800]=mean(b_in)
#define OFF_WINF  3584      // u16 [25][8][64][8]  W_in B-fragment-linear   (204800 B)
#define OFF_WEGF  208384    // u16 [6][17][64][8]  experts+gate frag-linear (104448 B)
#define OFF_WCTXF 312832    // u16 [2][8][64][8]   W_ctx frag-linear        (16384 B)
#define OFF_WOUTF 329216    // u16 [4][64][8]      W_out frag-linear        (4096 B)

__device__ __forceinline__ u16 f2bf(float x) {
  union { float f; u32 u; } v; v.f = x;
  u32 r = v.u + 0x7FFFu + ((v.u >> 16) & 1u);   // RNE
  return (u16)(r >> 16);
}

// ------------------------------------------------------------------
// Prep: wmean for the exact fp32 t path; all weights -> bf16 in
// MFMA-B-fragment-linear order: frag[tile][lane][j] with
// k = kt*32 + (lane>>4)*8 + j, n = ct*16 + (lane&15).
// ------------------------------------------------------------------
__global__ void prep_kernel(const float* __restrict__ W_in, const float* __restrict__ b_in,
                            const float* __restrict__ W_gate, const float* __restrict__ W_exp,
                            const float* __restrict__ W_ctx, const float* __restrict__ W_out,
                            float* __restrict__ wm, u16* __restrict__ WinF,
                            u16* __restrict__ WegF, u16* __restrict__ WctxF,
                            u16* __restrict__ WoutF) {
  int idx = blockIdx.x * 256 + threadIdx.x;
  if (idx < 801) {
    if (idx == 800) {
      float s = 0.f;
      for (int j = 0; j < 128; ++j) s += b_in[j];
      wm[800] = s * (1.f / 128.f);
    } else if (idx >= 784) {
      wm[idx] = 0.f;
    } else {
      float s = 0.f;
      for (int j = 0; j < 128; ++j) s += W_in[idx * 128 + j];
      wm[idx] = s * (1.f / 128.f);
    }
  } else if (idx < 103201) {                    // WinF: 25*8 tiles
    int f = idx - 801;
    int j = f & 7, lane = (f >> 3) & 63, tile = f >> 9;
    int ct = tile & 7, kt = tile >> 3;
    int k = kt * 32 + ((lane >> 4) << 3) + j;
    int n = ct * 16 + (lane & 15);
    WinF[f] = (k < 784) ? f2bf(W_in[k * 128 + n]) : (u16)0;
  } else if (idx < 155425) {                    // WegF: 6*17 tiles
    int f = idx - 103201;
    int j = f & 7, lane = (f >> 3) & 63, tile = f >> 9;
    int kt = tile / 17, ct = tile - kt * 17;
    int k = kt * 32 + ((lane >> 4) << 3) + j;
    int n = ct * 16 + (lane & 15);
    float v = 0.f;
    if (n < 256) { int e = n >> 6, h = n & 63; v = W_exp[(e * 192 + k) * 64 + h]; }
    else if (n < 260) v = W_gate[k * 4 + (n - 256)];
    WegF[f] = f2bf(v);
  } else if (idx < 163617) {                    // WctxF: 2*8 tiles
    int f = idx - 155425;
    int j = f & 7, lane = (f >> 3) & 63, tile = f >> 9;
    int ct = tile & 7, kt = tile >> 3;
    int k = kt * 32 + ((lane >> 4) << 3) + j;
    int n = ct * 16 + (lane & 15);
    WctxF[f] = f2bf(W_ctx[k * 128 + n]);
  } else if (idx < 165665) {                    // WoutF: 4 tiles (N padded 3->16)
    int f = idx - 163617;
    int j = f & 7, lane = (f >> 3) & 63, kt = f >> 9;
    int k = kt * 32 + ((lane >> 4) << 3) + j;
    int n = lane & 15;
    WoutF[f] = (n < 3) ? f2bf(W_out[k * 3 + n]) : (u16)0;
  }
}

// ------------------------------------------------------------------
// Fused forward, barrier-free: 4 waves/WG, each wave owns 16 rows.
// Per-wave private LDS block (3840 u16 = 7680 B):
//   enh  [6][16][40]  (full block)            -- phase 1 -> phase 2
//   cmb  [2][16][40]  (aliases u16 [0,1280))  -- phase 2 -> phase 3
//   ctx  [16][136]    (aliases u16 [1280,3456)) -- phase 3 -> phase 4
// Aliasing is safe: same-wave DS ops are processed in order.
// ------------------------------------------------------------------
__global__ __launch_bounds__(256, 4)
void fused_kernel(const float* __restrict__ x,
                  const float* __restrict__ b_in, const float* __restrict__ b_gate,
                  const float* __restrict__ b_exp, const float* __restrict__ b_ctx,
                  const float* __restrict__ b_out,
                  const float* __restrict__ wm, const u16* __restrict__ WinF,
                  const u16* __restrict__ WegF, const u16* __restrict__ WctxF,
                  const u16* __restrict__ WoutF,
                  float* __restrict__ out) {
  __shared__ __align__(16) u16 smem[4 * 3840];
  const int tid = threadIdx.x;
  const int wv = tid >> 6;
  const int ln = tid & 63;
  const int cb = ln & 15;        // fragment col / A-row
  const int qr = ln >> 4;        // k-quad
  u16* enhW = smem + wv * 3840;
  u16* cmbW = enhW;
  u16* ctxW = enhW + 1280;

  const int grow = blockIdx.x * 64 + wv * 16;     // this wave's first row
  const float* xr = x + (size_t)(grow + cb) * 784;

  const f32x4 vz = {0.f, 0.f, 0.f, 0.f};

  // ---- Phase 1: projected = x @ W_in (MFMA) + exact fp32 t ----
  f32x4 acc[8];
  #pragma unroll
  for (int i = 0; i < 8; ++i) acc[i] = vz;
  float tp = 0.f;

  for (int kt = 0; kt < 25; ++kt) {
    const int k0 = kt * 32 + qr * 8;
    float4 a0 = make_float4(0.f, 0.f, 0.f, 0.f);
    float4 a1 = make_float4(0.f, 0.f, 0.f, 0.f);
    if (k0 < 784) {                       // K-tail 784..799: zero A (WinF pad also 0)
      a0 = *(const float4*)(xr + k0);
      a1 = *(const float4*)(xr + k0 + 4);
      const float4 m0 = *(const float4*)(wm + k0);
      const float4 m1 = *(const float4*)(wm + k0 + 4);
      tp += a0.x * m0.x + a0.y * m0.y + a0.z * m0.z + a0.w * m0.w
          + a1.x * m1.x + a1.y * m1.y + a1.z * m1.z + a1.w * m1.w;
    }
    union { short8 s; u32 u[4]; } af;
    af.u[0] = (u32)f2bf(a0.x) | ((u32)f2bf(a0.y) << 16);
    af.u[1] = (u32)f2bf(a0.z) | ((u32)f2bf(a0.w) << 16);
    af.u[2] = (u32)f2bf(a1.x) | ((u32)f2bf(a1.y) << 16);
    af.u[3] = (u32)f2bf(a1.z) | ((u32)f2bf(a1.w) << 16);
    const u16* wb = WinF + (size_t)kt * 8 * 512 + ln * 8;
    #pragma unroll
    for (int ct = 0; ct < 8; ++ct) {
      short8 Bf = *(const short8*)(wb + ct * 512);
      acc[ct] = __builtin_amdgcn_mfma_f32_16x16x32_bf16(af.s, Bf, acc[ct], 0, 0, 0);
    }
  }

  // t: reduce partials across the 4 k-quads of row cb (all 4 copies get the sum)
  tp += __shfl_xor(tp, 16);
  tp += __shfl_xor(tp, 32);
  const float t = tp + wm[800];

  // enhanced[cols 0..127] = projected + b_in  (bf16, chunked [6][16][40])
  #pragma unroll
  for (int ct = 0; ct < 8; ++ct) {
    float bi = b_in[ct * 16 + cb];
    u16* dst = enhW + (ct >> 1) * 640 + (ct & 1) * 16 + cb;
    #pragma unroll
    for (int i = 0; i < 4; ++i)
      dst[(qr * 4 + i) * 40] = f2bf(acc[ct][i] + bi);
  }
  // enhanced[cols 128..191] = phasor bank. Lane (qr,cb): row cb, harmonics qr*8+1..qr*8+8
  {
    float phi = 7.f * t;
    float ss, cc, sd, cd;
    sincosf(phi * (float)(qr * 8 + 1), &ss, &cc);
    sincosf(phi, &sd, &cd);
    u16* pc = enhW + 4 * 640 + cb * 40 + qr * 8;
    u16* ps = enhW + 5 * 640 + cb * 40 + qr * 8;
    #pragma unroll
    for (int m = 0; m < 8; ++m) {
      pc[m] = f2bf(cc);
      ps[m] = f2bf(ss);
      float nc = cc * cd - ss * sd;
      ss = ss * cd + cc * sd;
      cc = nc;
    }
  }

  // ---- Phase 2: gate + experts over enhanced (K=192) ----
  f32x4 accg = vz;
  #pragma unroll
  for (int kt = 0; kt < 6; ++kt) {
    short8 Af = *(const short8*)(enhW + kt * 640 + cb * 40 + qr * 8);
    short8 Bf = *(const short8*)(WegF + ((kt * 17 + 16) * 64 + ln) * 8);
    accg = __builtin_amdgcn_mfma_f32_16x16x32_bf16(Af, Bf, accg, 0, 0, 0);
  }
  // softmax over expert lanes cb=0..3 of each quad, then broadcast to all lanes
  float ge[4][4];                          // [expert][i]
  {
    float bg = b_gate[cb & 3];
    #pragma unroll
    for (int i = 0; i < 4; ++i) {
      float gi = accg[i] + bg;
      float mx = fmaxf(gi, __shfl_xor(gi, 1));
      mx = fmaxf(mx, __shfl_xor(mx, 2));
      float ev = __expf(gi - mx);
      float sv = ev + __shfl_xor(ev, 1);
      sv += __shfl_xor(sv, 2);
      float g = ev / sv;
      int base = qr * 16;
      ge[0][i] = __shfl(g, base + 0);
      ge[1][i] = __shfl(g, base + 1);
      ge[2][i] = __shfl(g, base + 2);
      ge[3][i] = __shfl(g, base + 3);
    }
  }
  // experts one at a time (keeps live regs low), combine incrementally
  f32x4 cmb[4];
  #pragma unroll
  for (int i = 0; i < 4; ++i) cmb[i] = vz;
  #pragma unroll
  for (int e = 0; e < 4; ++e) {
    f32x4 ae[4];
    #pragma unroll
    for (int i = 0; i < 4; ++i) ae[i] = vz;
    #pragma unroll
    for (int kt = 0; kt < 6; ++kt) {
      short8 Af = *(const short8*)(enhW + kt * 640 + cb * 40 + qr * 8);
      #pragma unroll
      for (int c2 = 0; c2 < 4; ++c2) {
        short8 Bf = *(const short8*)(WegF + ((kt * 17 + e * 4 + c2) * 64 + ln) * 8);
        ae[c2] = __builtin_amdgcn_mfma_f32_16x16x32_bf16(Af, Bf, ae[c2], 0, 0, 0);
      }
    }
    #pragma unroll
    for (int c2 = 0; c2 < 4; ++c2) {
      float be = b_exp[e * 64 + c2 * 16 + cb];
      #pragma unroll
      for (int i = 0; i < 4; ++i)
        cmb[c2][i] += ge[e][i] * fmaxf(ae[c2][i] + be, 0.f);
    }
  }
  // combined -> LDS (bf16, [2][16][40]); all phase-2 enh reads precede these writes
  #pragma unroll
  for (int c2 = 0; c2 < 4; ++c2) {
    u16* dst = cmbW + (c2 >> 1) * 640 + (c2 & 1) * 16 + cb;
    #pragma unroll
    for (int i = 0; i < 4; ++i)
      dst[(qr * 4 + i) * 40] = f2bf(cmb[c2][i]);
  }

  // ---- Phase 3: ctx = tanh(combined @ W_ctx + b_ctx), K=64 ----
  f32x4 acc3[8];
  #pragma unroll
  for (int i = 0; i < 8; ++i) acc3[i] = vz;
  #pragma unroll
  for (int kt = 0; kt < 2; ++kt) {
    short8 Af = *(const short8*)(cmbW + kt * 640 + cb * 40 + qr * 8);
    #pragma unroll
    for (int ct = 0; ct < 8; ++ct) {
      short8 Bf = *(const short8*)(WctxF + ((kt * 8 + ct) * 64 + ln) * 8);
      acc3[ct] = __builtin_amdgcn_mfma_f32_16x16x32_bf16(Af, Bf, acc3[ct], 0, 0, 0);
    }
  }
  #pragma unroll
  for (int ct = 0; ct < 8; ++ct) {
    float bc = b_ctx[ct * 16 + cb];
    u16* dst = ctxW + ct * 16 + cb;
    #pragma unroll
    for (int i = 0; i < 4; ++i) {
      float v = acc3[ct][i] + bc;
      float ex = __expf(2.f * v);            // tanh via exp; saturates correctly
      dst[(qr * 4 + i) * 136] = f2bf(1.f - 2.f / (ex + 1.f));
    }
  }

  // ---- Phase 4: logits = ctx @ W_out + b_out (MFMA, N padded to 16) ----
  f32x4 acc4 = vz;
  #pragma unroll
  for (int kt = 0; kt < 4; ++kt) {
    short8 Af = *(const short8*)(ctxW + cb * 136 + kt * 32 + qr * 8);
    short8 Bf = *(const short8*)(WoutF + (kt * 64 + ln) * 8);
    acc4 = __builtin_amdgcn_mfma_f32_16x16x32_bf16(Af, Bf, acc4, 0, 0, 0);
  }
  if (cb < 3) {
    float bo = b_out[cb];
    #pragma unroll
    for (int i = 0; i < 4; ++i)
      out[(size_t)(grow + qr * 4 + i) * 3 + cb] = acc4[i] + bo;
  }
}

extern "C" void kernel_launch(void* const* d_in, const int* in_sizes, int n_in,
                              void* d_out, int out_size, void* d_ws, size_t ws_size,
                              hipStream_t stream) {
  const float* x      = (const float*)d_in[0];
  const float* W_in   = (const float*)d_in[1];
  const float* b_in   = (const float*)d_in[2];
  const float* W_gate = (const float*)d_in[3];
  const float* b_gate = (const float*)d_in[4];
  const float* W_exp  = (const float*)d_in[5];
  const float* b_exp  = (const float*)d_in[6];
  const float* W_ctx  = (const float*)d_in[7];
  const float* b_ctx  = (const float*)d_in[8];
  const float* W_out  = (const float*)d_in[9];
  const float* b_out  = (const float*)d_in[10];
  float* out = (float*)d_out;

  char* ws = (char*)d_ws;
  float* wm  = (float*)(ws + OFF_WM);
  u16* WinF  = (u16*)(ws + OFF_WINF);
  u16* WegF  = (u16*)(ws + OFF_WEGF);
  u16* WctxF = (u16*)(ws + OFF_WCTXF);
  u16* WoutF = (u16*)(ws + OFF_WOUTF);

  const int B = in_sizes[0] / 784;
  prep_kernel<<<648, 256, 0, stream>>>(W_in, b_in, W_gate, W_exp, W_ctx, W_out,
                                       wm, WinF, WegF, WctxF, WoutF);
  fused_kernel<<<B / 64, 256, 0, stream>>>(x, b_in, b_gate, b_exp, b_ctx, b_out,
                                           wm, WinF, WegF, WctxF, WoutF, out);
}